// Round 11
// baseline (135.924 us; speedup 1.0000x reference)
//
#include <hip/hip_runtime.h>
#include <hip/hip_bf16.h>
#include <math.h>

#define Bc 2
#define Nn 2048
#define Hh 256
#define NH 8
#define Dd 32
#define WIN 32
#define WL 65
#define BN (Bc * Nn)   // 4096

typedef __attribute__((ext_vector_type(8))) short bf16x8;
typedef __attribute__((ext_vector_type(4))) short s16x4;
typedef __attribute__((ext_vector_type(4))) float f32x4;

__device__ inline short f2bf(float f) {
    union { float f; unsigned u; } v; v.f = f;
    unsigned r = v.u + 0x7fffu + ((v.u >> 16) & 1u);
    return (short)(r >> 16);
}
__device__ inline float bf2f(short s) {
    union { float f; unsigned u; } v;
    v.u = ((unsigned)(unsigned short)s) << 16;
    return v.f;
}
__device__ inline bf16x8 cvt8(float4 a, float4 b) {
    union { __hip_bfloat162 h[4]; bf16x8 v; } u;
    u.h[0] = __float22bfloat162_rn(make_float2(a.x, a.y));
    u.h[1] = __float22bfloat162_rn(make_float2(a.z, a.w));
    u.h[2] = __float22bfloat162_rn(make_float2(b.x, b.y));
    u.h[3] = __float22bfloat162_rn(make_float2(b.z, b.w));
    return u.v;
}

// ================= L1: castx (vectorized, 8 ch/thread) + castw =================
// blocks [0,512): castx+norms; [512,1152): castw
__global__ __launch_bounds__(256) void castxw_kernel(
    const float* __restrict__ x, const float* __restrict__ alpha_norm,
    const float* __restrict__ Wq, const float* __restrict__ Wk, const float* __restrict__ Wv,
    const float* __restrict__ Wvec, const float* __restrict__ Wg, const float* __restrict__ Wo,
    short* __restrict__ xs_bf, short* __restrict__ vec_bf,
    float* __restrict__ vec_norm, short* __restrict__ inv_bf,
    short* __restrict__ WqkvT, short* __restrict__ WvecT,
    short* __restrict__ WgT, short* __restrict__ WoT) {
    __shared__ float Ts[32][33];
    const int t = threadIdx.x;
    if (blockIdx.x < 512) {
        const int idx = blockIdx.x * 256 + t;
        const int bn = idx >> 5, c8 = (idx & 31) * 8;
        const float* xp = &x[(size_t)bn * 1024 + c8];
        const float4 s0 = *(const float4*)xp,         s1 = *(const float4*)(xp + 4);
        const float4 a0 = *(const float4*)(xp + 256), a1 = *(const float4*)(xp + 260);
        const float4 b0 = *(const float4*)(xp + 512), b1 = *(const float4*)(xp + 516);
        const float4 c0 = *(const float4*)(xp + 768), c1 = *(const float4*)(xp + 772);
        *(bf16x8*)&xs_bf[(size_t)bn * 256 + c8] = cvt8(s0, s1);
        *(bf16x8*)&vec_bf[((size_t)0 * BN + bn) * 256 + c8] = cvt8(a0, a1);
        *(bf16x8*)&vec_bf[((size_t)1 * BN + bn) * 256 + c8] = cvt8(b0, b1);
        *(bf16x8*)&vec_bf[((size_t)2 * BN + bn) * 256 + c8] = cvt8(c0, c1);
        float4 n0, n1;
        n0.x = sqrtf(a0.x * a0.x + b0.x * b0.x + c0.x * c0.x);
        n0.y = sqrtf(a0.y * a0.y + b0.y * b0.y + c0.y * c0.y);
        n0.z = sqrtf(a0.z * a0.z + b0.z * b0.z + c0.z * c0.z);
        n0.w = sqrtf(a0.w * a0.w + b0.w * b0.w + c0.w * c0.w);
        n1.x = sqrtf(a1.x * a1.x + b1.x * b1.x + c1.x * c1.x);
        n1.y = sqrtf(a1.y * a1.y + b1.y * b1.y + c1.y * c1.y);
        n1.z = sqrtf(a1.z * a1.z + b1.z * b1.z + c1.z * c1.z);
        n1.w = sqrtf(a1.w * a1.w + b1.w * b1.w + c1.w * c1.w);
        *(float4*)&vec_norm[(size_t)bn * 256 + c8] = n0;
        *(float4*)&vec_norm[(size_t)bn * 256 + c8 + 4] = n1;
        const float an = alpha_norm[0];
        float4 m0, m1;
        m0.x = an * n0.x; m0.y = an * n0.y; m0.z = an * n0.z; m0.w = an * n0.w;
        m1.x = an * n1.x; m1.y = an * n1.y; m1.z = an * n1.z; m1.w = an * n1.w;
        *(bf16x8*)&inv_bf[(size_t)bn * 512 + 256 + c8] = cvt8(m0, m1);
        return;
    }
    const int cc = t & 31, r0 = t >> 5;
    const int id = blockIdx.x - 512;
    const float* W; int ldw; short* WT; int ldwt; int n0s, k0, n0d;
    if (id < 192) {            // [Wq|Wk|Wv] 256x768 -> WqkvT 768x256
        const int tn = id >> 3, tk = id & 7, sel = tn >> 3;
        W = sel == 0 ? Wq : (sel == 1 ? Wk : Wv); ldw = 256;
        n0s = (tn & 7) * 32; k0 = tk * 32; WT = WqkvT; ldwt = 256; n0d = tn * 32;
    } else if (id < 320) {     // Wvec 256x512 -> WvecT 512x256
        const int id2 = id - 192, tn = id2 >> 3, tk = id2 & 7;
        W = Wvec; ldw = 512; n0s = tn * 32; k0 = tk * 32; WT = WvecT; ldwt = 256; n0d = n0s;
    } else if (id < 448) {     // Wg 512x256 -> WgT 256x512
        const int id3 = id - 320, tn = id3 >> 4, tk = id3 & 15;
        W = Wg; ldw = 256; n0s = tn * 32; k0 = tk * 32; WT = WgT; ldwt = 512; n0d = n0s;
    } else {                   // Wo 256x768 -> WoT 768x256
        const int id4 = id - 448, tn = id4 >> 3, tk = id4 & 7;
        W = Wo; ldw = 768; n0s = tn * 32; k0 = tk * 32; WT = WoT; ldwt = 256; n0d = n0s;
    }
#pragma unroll
    for (int p = 0; p < 4; ++p) {
        const int rr = r0 + p * 8;
        Ts[rr][cc] = W[(size_t)(k0 + rr) * ldw + n0s + cc];
    }
    __syncthreads();
#pragma unroll
    for (int p = 0; p < 4; ++p) {
        const int rr = r0 + p * 8;
        WT[(size_t)(n0d + rr) * ldwt + k0 + cc] = f2bf(Ts[cc][rr]);
    }
}

// ================= L2: qkv GEMM + vecdot GEMM =================
// blocks [0,384): qkv (64x128 tiles, A = xs_bf)
// blocks [384,896): vecdot (16 rows x 128 ch x 2 halves, A = vec_bf)
__global__ __launch_bounds__(256) void fused_mid(
    const short* __restrict__ xs_bf, const short* __restrict__ vec_bf,
    const short* __restrict__ WqkvT, const short* __restrict__ WvecT,
    const float* __restrict__ bq, const float* __restrict__ bk, const float* __restrict__ bv,
    const float* __restrict__ alpha_dot,
    short* __restrict__ Qb, short* __restrict__ Kb, short* __restrict__ Vb,
    float* __restrict__ vec_dot, short* __restrict__ inv_bf) {
    __shared__ __align__(16) short lds[22912];  // 45.8 KB
    const int bid = blockIdx.x;
    const int t = threadIdx.x, lane = t & 63, wid = t >> 6;
    const int quad = lane >> 4, lm = lane & 15;

    if (bid < 384) {
        // ----- qkv: tile 64x128, A bf16 from xs_bf -----
        short* As = lds;           // 2560
        short* Bs = lds + 2560;    // 5120
        const int row0 = (bid & 63) * 64, col0 = (bid >> 6) * 128;
        const int wm = wid & 1, wn = wid >> 1;
        const int srow = t >> 2, scg = (t & 3) * 8;
        f32x4 acc[2][4];
#pragma unroll
        for (int mt = 0; mt < 2; ++mt)
#pragma unroll
            for (int nt = 0; nt < 4; ++nt) {
                f32x4 z = {0.f, 0.f, 0.f, 0.f};
                acc[mt][nt] = z;
            }
        bf16x8 pa = *(const bf16x8*)&xs_bf[(size_t)(row0 + srow) * 256 + scg];
        bf16x8 pb[2];
#pragma unroll
        for (int p = 0; p < 2; ++p) {
            const int idx = t + p * 256;
            pb[p] = *(const bf16x8*)&WqkvT[(size_t)(col0 + (idx >> 2)) * 256 + (idx & 3) * 8];
        }
        for (int k0 = 0; k0 < 256; k0 += 32) {
            *(bf16x8*)&As[srow * 40 + scg] = pa;
#pragma unroll
            for (int p = 0; p < 2; ++p) {
                const int idx = t + p * 256;
                *(bf16x8*)&Bs[(idx >> 2) * 40 + (idx & 3) * 8] = pb[p];
            }
            __syncthreads();
            if (k0 + 32 < 256) {
                pa = *(const bf16x8*)&xs_bf[(size_t)(row0 + srow) * 256 + k0 + 32 + scg];
#pragma unroll
                for (int p = 0; p < 2; ++p) {
                    const int idx = t + p * 256;
                    pb[p] = *(const bf16x8*)&WqkvT[(size_t)(col0 + (idx >> 2)) * 256 + k0 + 32 + (idx & 3) * 8];
                }
            }
            bf16x8 af[2], bfr[4];
#pragma unroll
            for (int mt = 0; mt < 2; ++mt)
                af[mt] = *(bf16x8*)&As[(wm * 32 + mt * 16 + lm) * 40 + quad * 8];
#pragma unroll
            for (int nt = 0; nt < 4; ++nt)
                bfr[nt] = *(bf16x8*)&Bs[(wn * 64 + nt * 16 + lm) * 40 + quad * 8];
#pragma unroll
            for (int mt = 0; mt < 2; ++mt)
#pragma unroll
                for (int nt = 0; nt < 4; ++nt)
                    acc[mt][nt] = __builtin_amdgcn_mfma_f32_16x16x32_bf16(
                        af[mt], bfr[nt], acc[mt][nt], 0, 0, 0);
            __syncthreads();
        }
        const int chunk = col0 >> 8;
        short* dst = chunk == 0 ? Qb : (chunk == 1 ? Kb : Vb);
        const float* bias = chunk == 0 ? bq : (chunk == 1 ? bk : bv);
#pragma unroll
        for (int mt = 0; mt < 2; ++mt)
#pragma unroll
            for (int nt = 0; nt < 4; ++nt) {
                const int cm = (col0 + wn * 64 + nt * 16 + lm) & 255;
                const float bb = bias[cm];
#pragma unroll
                for (int r = 0; r < 4; ++r) {
                    const int row = row0 + wm * 32 + mt * 16 + quad * 4 + r;
                    dst[(size_t)row * 256 + cm] = f2bf(acc[mt][nt][r] + bb);
                }
            }
        return;
    }

    // ----- vecdot: 16 rows x (128 ch x 2 halves); A staged once -----
    short* As = lds;            // 3 x 16 x 264 = 12672
    short* Bs = lds + 12672;    // 2 x 128 x 40 = 10240
    const int vb = bid - 384;
    const int row0 = (vb >> 1) * 16, ch0 = (vb & 1) * 128;

#pragma unroll
    for (int q = 0; q < 6; ++q) {
        const int idx = t + q * 256;          // [0,1536)
        const int p = idx >> 9, rem = idx & 511, row = rem >> 5, kg = rem & 31;
        *(bf16x8*)&As[(p * 16 + row) * 264 + kg * 8] =
            *(const bf16x8*)&vec_bf[((size_t)p * BN + row0 + row) * 256 + kg * 8];
    }
    f32x4 acc[3][2][2];  // [plane][half][nt]
#pragma unroll
    for (int p = 0; p < 3; ++p)
#pragma unroll
        for (int h = 0; h < 2; ++h)
#pragma unroll
            for (int nt = 0; nt < 2; ++nt) {
                f32x4 z = {0.f, 0.f, 0.f, 0.f};
                acc[p][h][nt] = z;
            }
    bf16x8 pb[4];
#pragma unroll
    for (int q = 0; q < 4; ++q) {
        const int idx = t + q * 256;          // [0,1024)
        const int h = idx >> 9, rem = idx & 511, c = rem >> 2, kg = rem & 3;
        pb[q] = *(const bf16x8*)&WvecT[(size_t)(h * 256 + ch0 + c) * 256 + kg * 8];
    }
    __syncthreads();
    for (int k0 = 0; k0 < 256; k0 += 32) {
#pragma unroll
        for (int q = 0; q < 4; ++q) {
            const int idx = t + q * 256;
            const int h = idx >> 9, rem = idx & 511, c = rem >> 2, kg = rem & 3;
            *(bf16x8*)&Bs[(h * 128 + c) * 40 + kg * 8] = pb[q];
        }
        __syncthreads();
        if (k0 + 32 < 256) {
#pragma unroll
            for (int q = 0; q < 4; ++q) {
                const int idx = t + q * 256;
                const int h = idx >> 9, rem = idx & 511, c = rem >> 2, kg = rem & 3;
                pb[q] = *(const bf16x8*)&WvecT[(size_t)(h * 256 + ch0 + c) * 256 + k0 + 32 + kg * 8];
            }
        }
        bf16x8 af[3], bfr[2][2];
#pragma unroll
        for (int p = 0; p < 3; ++p)
            af[p] = *(bf16x8*)&As[(p * 16 + lm) * 264 + k0 + quad * 8];
#pragma unroll
        for (int h = 0; h < 2; ++h)
#pragma unroll
            for (int nt = 0; nt < 2; ++nt)
                bfr[h][nt] = *(bf16x8*)&Bs[(h * 128 + wid * 32 + nt * 16 + lm) * 40 + quad * 8];
#pragma unroll
        for (int p = 0; p < 3; ++p)
#pragma unroll
            for (int h = 0; h < 2; ++h)
#pragma unroll
                for (int nt = 0; nt < 2; ++nt)
                    acc[p][h][nt] = __builtin_amdgcn_mfma_f32_16x16x32_bf16(
                        af[p], bfr[h][nt], acc[p][h][nt], 0, 0, 0);
        __syncthreads();
    }
    const float ad = alpha_dot[0];
#pragma unroll
    for (int nt = 0; nt < 2; ++nt) {
        const int col = ch0 + wid * 32 + nt * 16 + lm;
#pragma unroll
        for (int r = 0; r < 4; ++r) {
            const int row = row0 + quad * 4 + r;
            float dot = 0.f;
#pragma unroll
            for (int p = 0; p < 3; ++p)
                dot = fmaf(acc[p][0][nt][r], acc[p][1][nt][r], dot);
            vec_dot[(size_t)row * 256 + col] = dot;
            inv_bf[(size_t)row * 512 + col] = f2bf(ad * dot);
        }
    }
}

// ================= L3: gate GEMM + attention (parallel ranges) =================
// blocks [0,256): gate; [256,1280): attn
__global__ __launch_bounds__(256) void gate_attn_kernel(
    const short* __restrict__ inv_bf, const short* __restrict__ WgT,
    const float* __restrict__ bg,
    const short* __restrict__ Qb, const short* __restrict__ Kb,
    const short* __restrict__ Vb, const short* __restrict__ vec_bf,
    float* __restrict__ gate, float* __restrict__ attnw,
    short* __restrict__ vec_aggr_bf, short* __restrict__ xout_bf) {
    __shared__ __align__(16) short lds[21760];  // 43.5 KB
    const int bid = blockIdx.x;
    const int t = threadIdx.x, lane = t & 63, wid = t >> 6;
    const int wm = wid & 1, wn = wid >> 1, quad = lane >> 4, lm = lane & 15;

    if (bid < 256) {
        // ----- gate = sigmoid(inv @ Wg + bg), tile 64x64, K=512 -----
        short* As = lds;
        short* Bs = lds + 2560;
        const int row0 = (bid & 63) * 64, col0 = (bid >> 6) * 64;
        const int srow = t >> 2, scg = (t & 3) * 8;
        f32x4 acc[2][2];
#pragma unroll
        for (int mt = 0; mt < 2; ++mt)
#pragma unroll
            for (int nt = 0; nt < 2; ++nt) {
                f32x4 z = {0.f, 0.f, 0.f, 0.f};
                acc[mt][nt] = z;
            }
        bf16x8 pa = *(const bf16x8*)&inv_bf[(size_t)(row0 + srow) * 512 + scg];
        bf16x8 pb = *(const bf16x8*)&WgT[(size_t)(col0 + srow) * 512 + scg];
        for (int k0 = 0; k0 < 512; k0 += 32) {
            *(bf16x8*)&As[srow * 40 + scg] = pa;
            *(bf16x8*)&Bs[srow * 40 + scg] = pb;
            __syncthreads();
            if (k0 + 32 < 512) {
                pa = *(const bf16x8*)&inv_bf[(size_t)(row0 + srow) * 512 + k0 + 32 + scg];
                pb = *(const bf16x8*)&WgT[(size_t)(col0 + srow) * 512 + k0 + 32 + scg];
            }
            bf16x8 af[2], bfr[2];
#pragma unroll
            for (int mt = 0; mt < 2; ++mt)
                af[mt] = *(bf16x8*)&As[(wm * 32 + mt * 16 + lm) * 40 + quad * 8];
#pragma unroll
            for (int nt = 0; nt < 2; ++nt)
                bfr[nt] = *(bf16x8*)&Bs[(wn * 32 + nt * 16 + lm) * 40 + quad * 8];
#pragma unroll
            for (int mt = 0; mt < 2; ++mt)
#pragma unroll
                for (int nt = 0; nt < 2; ++nt)
                    acc[mt][nt] = __builtin_amdgcn_mfma_f32_16x16x32_bf16(
                        af[mt], bfr[nt], acc[mt][nt], 0, 0, 0);
            __syncthreads();
        }
#pragma unroll
        for (int mt = 0; mt < 2; ++mt)
#pragma unroll
            for (int nt = 0; nt < 2; ++nt) {
                const int col = col0 + wn * 32 + nt * 16 + lm;
                const float bb = bg[col];
#pragma unroll
                for (int r = 0; r < 4; ++r) {
                    const int row = row0 + wm * 32 + mt * 16 + quad * 4 + r;
                    const float z = acc[mt][nt][r] + bb;
                    gate[(size_t)row * 256 + col] = 1.f / (1.f + __expf(-z));
                }
            }
        return;
    }

    // ----- attention -----
    short* Qs = lds;            // 32*40
    short* Ks = lds + 1280;     // 96*40
    short* Pb = lds + 5120;     // 32*104
    short* St = lds + 8448;     // 128*104
    const int ab = bid - 256;
    const int bh = ab >> 6, tile = ab & 63;
    const int b = bh >> 3, hd = bh & 7;
    const int i0 = tile * 32;

    for (int idx = t; idx < 32 * 104 / 2; idx += 256) ((int*)Pb)[idx] = 0;
    if (t < 128) {
        const int row = t >> 2, cg = t & 3;
        *(bf16x8*)&Qs[row * 40 + cg * 8] =
            *(const bf16x8*)&Qb[((size_t)(b * Nn + i0 + row)) * 256 + hd * 32 + cg * 8];
    }
#pragma unroll
    for (int kk = 0; kk < 2; ++kk) {
        const int idx = t + kk * 256;
        if (idx < 384) {
            const int row = idx >> 2, cg = idx & 3;
            const int j = i0 - WIN + row;
            bf16x8 kv = {0, 0, 0, 0, 0, 0, 0, 0};
            if (j >= 0 && j < Nn)
                kv = *(const bf16x8*)&Kb[((size_t)(b * Nn + j)) * 256 + hd * 32 + cg * 8];
            *(bf16x8*)&Ks[row * 40 + cg * 8] = kv;
        }
    }
    __syncthreads();

    if (wid < 2) {
        const int il0 = wid * 16;
        const bf16x8 aq = *(bf16x8*)&Qs[(il0 + lm) * 40 + quad * 8];
        f32x4 c[6];
#pragma unroll
        for (int nt = 0; nt < 6; ++nt) {
            const bf16x8 bk = *(bf16x8*)&Ks[(nt * 16 + lm) * 40 + quad * 8];
            f32x4 z = {0.f, 0.f, 0.f, 0.f};
            c[nt] = __builtin_amdgcn_mfma_f32_16x16x32_bf16(aq, bk, z, 0, 0, 0);
        }
        float mx[4] = {-1e30f, -1e30f, -1e30f, -1e30f};
#pragma unroll
        for (int nt = 0; nt < 6; ++nt)
#pragma unroll
            for (int r = 0; r < 4; ++r) {
                const int il = il0 + quad * 4 + r;
                const int w = nt * 16 + lm - il;
                const float v = (w >= 0 && w <= 64)
                    ? c[nt][r] * 0.17677669529663687f : -1e30f;
                c[nt][r] = v;
                mx[r] = fmaxf(mx[r], v);
            }
#pragma unroll
        for (int off = 1; off < 16; off <<= 1)
#pragma unroll
            for (int r = 0; r < 4; ++r) mx[r] = fmaxf(mx[r], __shfl_xor(mx[r], off, 64));
        float sm[4] = {0.f, 0.f, 0.f, 0.f};
#pragma unroll
        for (int nt = 0; nt < 6; ++nt)
#pragma unroll
            for (int r = 0; r < 4; ++r) {
                const int il = il0 + quad * 4 + r;
                const int w = nt * 16 + lm - il;
                const float e = (w >= 0 && w <= 64) ? __expf(c[nt][r] - mx[r]) : 0.f;
                c[nt][r] = e;
                sm[r] += e;
            }
#pragma unroll
        for (int off = 1; off < 16; off <<= 1)
#pragma unroll
            for (int r = 0; r < 4; ++r) sm[r] += __shfl_xor(sm[r], off, 64);
        float inv[4];
#pragma unroll
        for (int r = 0; r < 4; ++r) inv[r] = 1.f / sm[r];
#pragma unroll
        for (int nt = 0; nt < 6; ++nt)
#pragma unroll
            for (int r = 0; r < 4; ++r) {
                const int il = il0 + quad * 4 + r;
                const int jr = nt * 16 + lm;
                const int w = jr - il;
                if (w >= 0 && w <= 64) {
                    const float pw = c[nt][r] * inv[r];
                    attnw[((size_t)bh * Nn + (i0 + il)) * WL + w] = pw;
                    Pb[il * 104 + jr] = f2bf(pw);
                }
            }
    } else {
        // stage S^T: V dims 0-31, vec dims 32-127; packed 4-j b64 writes
        const int tt = t - 128;
        const int chunk = tt >> 3;        // 16 chunks of 8 dims
        const int j4 = (tt & 7) * 4;      // 4 consecutive j per iter
#pragma unroll
        for (int it = 0; it < 3; ++it) {
            const int jr = j4 + it * 32;
            bf16x8 v[4];
#pragma unroll
            for (int q = 0; q < 4; ++q) {
                const int j = i0 - WIN + jr + q;
                bf16x8 val = {0, 0, 0, 0, 0, 0, 0, 0};
                if (j >= 0 && j < Nn) {
                    if (chunk < 4) {
                        val = *(const bf16x8*)&Vb[((size_t)(b * Nn + j)) * 256 + hd * 32 + chunk * 8];
                    } else {
                        const int vc = (chunk - 4) >> 2, d0 = ((chunk - 4) & 3) * 8;
                        val = *(const bf16x8*)&vec_bf[((size_t)vc * BN + b * Nn + j) * 256 + hd * 32 + d0];
                    }
                }
                v[q] = val;
            }
#pragma unroll
            for (int u = 0; u < 8; ++u) {
                s16x4 pk;
                pk[0] = v[0][u]; pk[1] = v[1][u]; pk[2] = v[2][u]; pk[3] = v[3][u];
                *(s16x4*)&St[(chunk * 8 + u) * 104 + jr] = pk;
            }
        }
    }
    __syncthreads();

    f32x4 acc[4];
#pragma unroll
    for (int nt = 0; nt < 4; ++nt) {
        f32x4 z = {0.f, 0.f, 0.f, 0.f};
        acc[nt] = z;
    }
#pragma unroll
    for (int ks = 0; ks < 3; ++ks) {
        const bf16x8 ap = *(bf16x8*)&Pb[(wm * 16 + lm) * 104 + ks * 32 + quad * 8];
#pragma unroll
        for (int nt = 0; nt < 4; ++nt) {
            const bf16x8 bs = *(bf16x8*)&St[(wn * 64 + nt * 16 + lm) * 104 + ks * 32 + quad * 8];
            acc[nt] = __builtin_amdgcn_mfma_f32_16x16x32_bf16(ap, bs, acc[nt], 0, 0, 0);
        }
    }
#pragma unroll
    for (int nt = 0; nt < 4; ++nt) {
        const int dim = wn * 64 + nt * 16 + lm;
#pragma unroll
        for (int r = 0; r < 4; ++r) {
            const int i = wm * 16 + quad * 4 + r;
            const size_t bn = (size_t)(b * Nn + i0 + i);
            if (dim < 32) {
                xout_bf[bn * 256 + hd * 32 + dim] = f2bf(acc[nt][r]);
            } else {
                const int dm = dim - 32, c = dm >> 5, dd = dm & 31;
                vec_aggr_bf[((size_t)c * BN + bn) * 256 + hd * 32 + dd] = f2bf(acc[nt][r]);
            }
        }
    }
}

// ================= L4: out projection + scalar combine + vec gating =========
// 512 blocks: 128 row-tiles (32 rows) x 4 col-tiles (64 cols)
__global__ __launch_bounds__(256) void out_kernel(
    const short* __restrict__ A, const short* __restrict__ BT,
    const float* __restrict__ bo,
    const float* __restrict__ vec_dot, const float* __restrict__ vec_norm,
    const float* __restrict__ gate, const short* __restrict__ vec_aggr_bf,
    const float* __restrict__ x, float* __restrict__ out) {
    __shared__ __align__(16) short As[32 * 40];
    __shared__ __align__(16) short Bs[3][64 * 40];
    const int row0 = (blockIdx.x & 127) * 32, ch0 = (blockIdx.x >> 7) * 64;
    const int t = threadIdx.x, lane = t & 63, wid = t >> 6;
    const int wm = wid & 1, wn = wid >> 1, quad = lane >> 4, lm = lane & 15;
    f32x4 acc[3][2];
#pragma unroll
    for (int p = 0; p < 3; ++p)
#pragma unroll
        for (int nt = 0; nt < 2; ++nt) {
            f32x4 z = {0.f, 0.f, 0.f, 0.f};
            acc[p][nt] = z;
        }
    bf16x8 pa = {0, 0, 0, 0, 0, 0, 0, 0};
    const int arow = t >> 2, acg = (t & 3) * 8;
    if (t < 128) pa = *(const bf16x8*)&A[(size_t)(row0 + arow) * 256 + acg];
    bf16x8 pb[3];
#pragma unroll
    for (int q = 0; q < 3; ++q) {
        const int idx = t + q * 256;
        const int p = idx >> 8, rem = idx & 255, brow = rem >> 2, bkg = (rem & 3) * 8;
        pb[q] = *(const bf16x8*)&BT[(size_t)(p * 256 + ch0 + brow) * 256 + bkg];
    }
    for (int k0 = 0; k0 < 256; k0 += 32) {
        if (t < 128) *(bf16x8*)&As[arow * 40 + acg] = pa;
#pragma unroll
        for (int q = 0; q < 3; ++q) {
            const int idx = t + q * 256;
            const int p = idx >> 8, rem = idx & 255, brow = rem >> 2, bkg = (rem & 3) * 8;
            *(bf16x8*)&Bs[p][brow * 40 + bkg] = pb[q];
        }
        __syncthreads();
        if (k0 + 32 < 256) {
            if (t < 128) pa = *(const bf16x8*)&A[(size_t)(row0 + arow) * 256 + k0 + 32 + acg];
#pragma unroll
            for (int q = 0; q < 3; ++q) {
                const int idx = t + q * 256;
                const int p = idx >> 8, rem = idx & 255, brow = rem >> 2, bkg = (rem & 3) * 8;
                pb[q] = *(const bf16x8*)&BT[(size_t)(p * 256 + ch0 + brow) * 256 + k0 + 32 + bkg];
            }
        }
        const bf16x8 af = *(bf16x8*)&As[(wm * 16 + lm) * 40 + quad * 8];
        bf16x8 bfr[3][2];
#pragma unroll
        for (int p = 0; p < 3; ++p)
#pragma unroll
            for (int nt = 0; nt < 2; ++nt)
                bfr[p][nt] = *(bf16x8*)&Bs[p][(wn * 32 + nt * 16 + lm) * 40 + quad * 8];
#pragma unroll
        for (int p = 0; p < 3; ++p)
#pragma unroll
            for (int nt = 0; nt < 2; ++nt)
                acc[p][nt] = __builtin_amdgcn_mfma_f32_16x16x32_bf16(
                    af, bfr[p][nt], acc[p][nt], 0, 0, 0);
        __syncthreads();
    }
#pragma unroll
    for (int nt = 0; nt < 2; ++nt) {
        const int col = ch0 + wn * 32 + nt * 16 + lm;
        const float b1 = bo[col], b2 = bo[256 + col], b3 = bo[512 + col];
#pragma unroll
        for (int r = 0; r < 4; ++r) {
            const int row = row0 + wm * 16 + quad * 4 + r;
            const float o1 = acc[0][nt][r] + b1;
            const float o2 = acc[1][nt][r] + b2;
            const float o3 = acc[2][nt][r] + b3;
            const float vd = vec_dot[(size_t)row * 256 + col];
            const float vn = vec_norm[(size_t)row * 256 + col];
            out[(size_t)row * 1024 + col] = vd * o1 + vn * o2 + o3;
        }
    }
    // vec channels: out = gate * vec_aggr + vec (32x64 tile per plane)
#pragma unroll
    for (int c = 0; c < 3; ++c) {
#pragma unroll
        for (int it = 0; it < 2; ++it) {
            const int idx = t + it * 256;
            const int row = row0 + (idx >> 4), col = ch0 + (idx & 15) * 4;
            const float4 g4 = *(const float4*)&gate[(size_t)row * 256 + col];
            const s16x4 va = *(const s16x4*)&vec_aggr_bf[((size_t)c * BN + row) * 256 + col];
            const float4 xv = *(const float4*)&x[(size_t)row * 1024 + (1 + c) * 256 + col];
            float4 o;
            o.x = fmaf(g4.x, bf2f(va[0]), xv.x);
            o.y = fmaf(g4.y, bf2f(va[1]), xv.y);
            o.z = fmaf(g4.z, bf2f(va[2]), xv.z);
            o.w = fmaf(g4.w, bf2f(va[3]), xv.w);
            *(float4*)&out[(size_t)row * 1024 + (1 + c) * 256 + col] = o;
        }
    }
}

extern "C" void kernel_launch(void* const* d_in, const int* in_sizes, int n_in,
                              void* d_out, int out_size, void* d_ws, size_t ws_size,
                              hipStream_t stream) {
    const float* x  = (const float*)d_in[0];
    const float* Wq = (const float*)d_in[1];
    const float* bq = (const float*)d_in[2];
    const float* Wk = (const float*)d_in[3];
    const float* bk = (const float*)d_in[4];
    const float* Wv = (const float*)d_in[5];
    const float* bv = (const float*)d_in[6];
    const float* Wo = (const float*)d_in[7];
    const float* bo = (const float*)d_in[8];
    const float* Wvec = (const float*)d_in[9];
    const float* alpha_dot  = (const float*)d_in[10];
    const float* alpha_norm = (const float*)d_in[11];
    const float* Wg = (const float*)d_in[12];
    const float* bg = (const float*)d_in[13];

    float* ws = (float*)d_ws;
    float* vec_dot  = ws;              // 1048576
    float* vec_norm = ws + 1048576;    // 1048576
    float* gate     = ws + 2097152;    // 1048576
    short* sb = (short*)(ws + 3145728);
    short* xs_bf       = sb;               // 1048576
    short* vec_bf      = sb + 1048576;     // 3145728
    short* inv_bf      = sb + 4194304;     // 2097152
    short* xout_bf     = sb + 6291456;     // 1048576
    short* Q_bf        = sb + 7340032;     // 1048576
    short* K_bf        = sb + 8388608;     // 1048576
    short* V_bf        = sb + 9437184;     // 1048576
    short* vec_aggr_bf = sb + 10485760;    // 3145728
    short* WqkvT       = sb + 13631488;    // 196608
    short* WvecT       = sb + 13828096;    // 131072
    short* WgT         = sb + 13959168;    // 131072
    short* WoT         = sb + 14090240;    // 196608

    float* out = (float*)d_out;
    float* attnw = out + (size_t)Bc * Nn * 4 * Hh;  // offset 4,194,304

    castxw_kernel<<<1152, 256, 0, stream>>>(x, alpha_norm, Wq, Wk, Wv, Wvec, Wg, Wo,
                                            xs_bf, vec_bf, vec_norm, inv_bf,
                                            WqkvT, WvecT, WgT, WoT);
    fused_mid<<<896, 256, 0, stream>>>(xs_bf, vec_bf, WqkvT, WvecT, bq, bk, bv,
                                       alpha_dot, Q_bf, K_bf, V_bf, vec_dot, inv_bf);
    gate_attn_kernel<<<1280, 256, 0, stream>>>(inv_bf, WgT, bg, Q_bf, K_bf, V_bf,
                                               vec_bf, gate, attnw, vec_aggr_bf, xout_bf);
    out_kernel<<<512, 256, 0, stream>>>(xout_bf, WoT, bo, vec_dot, vec_norm,
                                        gate, vec_aggr_bf, x, out);
}

// Round 12
// 133.548 us; speedup vs baseline: 1.0178x; 1.0178x over previous
//
#include <hip/hip_runtime.h>
#include <hip/hip_bf16.h>
#include <math.h>

#define Bc 2
#define Nn 2048
#define Hh 256
#define NH 8
#define Dd 32
#define WIN 32
#define WL 65
#define BN (Bc * Nn)   // 4096

typedef __attribute__((ext_vector_type(8))) short bf16x8;
typedef __attribute__((ext_vector_type(4))) short s16x4;
typedef __attribute__((ext_vector_type(4))) float f32x4;

__device__ inline short f2bf(float f) {
    union { float f; unsigned u; } v; v.f = f;
    unsigned r = v.u + 0x7fffu + ((v.u >> 16) & 1u);
    return (short)(r >> 16);
}
__device__ inline float bf2f(short s) {
    union { float f; unsigned u; } v;
    v.u = ((unsigned)(unsigned short)s) << 16;
    return v.f;
}
__device__ inline bf16x8 cvt8(float4 a, float4 b) {
    union { __hip_bfloat162 h[4]; bf16x8 v; } u;
    u.h[0] = __float22bfloat162_rn(make_float2(a.x, a.y));
    u.h[1] = __float22bfloat162_rn(make_float2(a.z, a.w));
    u.h[2] = __float22bfloat162_rn(make_float2(b.x, b.y));
    u.h[3] = __float22bfloat162_rn(make_float2(b.z, b.w));
    return u.v;
}

// ================= L1: castx (vectorized, 8 ch/thread) + castw =================
// blocks [0,512): castx+norms; [512,1152): castw
__global__ __launch_bounds__(256) void castxw_kernel(
    const float* __restrict__ x, const float* __restrict__ alpha_norm,
    const float* __restrict__ Wq, const float* __restrict__ Wk, const float* __restrict__ Wv,
    const float* __restrict__ Wvec, const float* __restrict__ Wg, const float* __restrict__ Wo,
    short* __restrict__ xs_bf, short* __restrict__ vec_bf,
    float* __restrict__ vec_norm, short* __restrict__ inv_bf,
    short* __restrict__ WqkvT, short* __restrict__ WvecT,
    short* __restrict__ WgT, short* __restrict__ WoT) {
    __shared__ float Ts[32][33];
    const int t = threadIdx.x;
    if (blockIdx.x < 512) {
        const int idx = blockIdx.x * 256 + t;
        const int bn = idx >> 5, c8 = (idx & 31) * 8;
        const float* xp = &x[(size_t)bn * 1024 + c8];
        const float4 s0 = *(const float4*)xp,         s1 = *(const float4*)(xp + 4);
        const float4 a0 = *(const float4*)(xp + 256), a1 = *(const float4*)(xp + 260);
        const float4 b0 = *(const float4*)(xp + 512), b1 = *(const float4*)(xp + 516);
        const float4 c0 = *(const float4*)(xp + 768), c1 = *(const float4*)(xp + 772);
        *(bf16x8*)&xs_bf[(size_t)bn * 256 + c8] = cvt8(s0, s1);
        *(bf16x8*)&vec_bf[((size_t)0 * BN + bn) * 256 + c8] = cvt8(a0, a1);
        *(bf16x8*)&vec_bf[((size_t)1 * BN + bn) * 256 + c8] = cvt8(b0, b1);
        *(bf16x8*)&vec_bf[((size_t)2 * BN + bn) * 256 + c8] = cvt8(c0, c1);
        float4 n0, n1;
        n0.x = sqrtf(a0.x * a0.x + b0.x * b0.x + c0.x * c0.x);
        n0.y = sqrtf(a0.y * a0.y + b0.y * b0.y + c0.y * c0.y);
        n0.z = sqrtf(a0.z * a0.z + b0.z * b0.z + c0.z * c0.z);
        n0.w = sqrtf(a0.w * a0.w + b0.w * b0.w + c0.w * c0.w);
        n1.x = sqrtf(a1.x * a1.x + b1.x * b1.x + c1.x * c1.x);
        n1.y = sqrtf(a1.y * a1.y + b1.y * b1.y + c1.y * c1.y);
        n1.z = sqrtf(a1.z * a1.z + b1.z * b1.z + c1.z * c1.z);
        n1.w = sqrtf(a1.w * a1.w + b1.w * b1.w + c1.w * c1.w);
        *(float4*)&vec_norm[(size_t)bn * 256 + c8] = n0;
        *(float4*)&vec_norm[(size_t)bn * 256 + c8 + 4] = n1;
        const float an = alpha_norm[0];
        float4 m0, m1;
        m0.x = an * n0.x; m0.y = an * n0.y; m0.z = an * n0.z; m0.w = an * n0.w;
        m1.x = an * n1.x; m1.y = an * n1.y; m1.z = an * n1.z; m1.w = an * n1.w;
        *(bf16x8*)&inv_bf[(size_t)bn * 512 + 256 + c8] = cvt8(m0, m1);
        return;
    }
    const int cc = t & 31, r0 = t >> 5;
    const int id = blockIdx.x - 512;
    const float* W; int ldw; short* WT; int ldwt; int n0s, k0, n0d;
    if (id < 192) {            // [Wq|Wk|Wv] 256x768 -> WqkvT 768x256
        const int tn = id >> 3, tk = id & 7, sel = tn >> 3;
        W = sel == 0 ? Wq : (sel == 1 ? Wk : Wv); ldw = 256;
        n0s = (tn & 7) * 32; k0 = tk * 32; WT = WqkvT; ldwt = 256; n0d = tn * 32;
    } else if (id < 320) {     // Wvec 256x512 -> WvecT 512x256
        const int id2 = id - 192, tn = id2 >> 3, tk = id2 & 7;
        W = Wvec; ldw = 512; n0s = tn * 32; k0 = tk * 32; WT = WvecT; ldwt = 256; n0d = n0s;
    } else if (id < 448) {     // Wg 512x256 -> WgT 256x512
        const int id3 = id - 320, tn = id3 >> 4, tk = id3 & 15;
        W = Wg; ldw = 256; n0s = tn * 32; k0 = tk * 32; WT = WgT; ldwt = 512; n0d = n0s;
    } else {                   // Wo 256x768 -> WoT 768x256
        const int id4 = id - 448, tn = id4 >> 3, tk = id4 & 7;
        W = Wo; ldw = 768; n0s = tn * 32; k0 = tk * 32; WT = WoT; ldwt = 256; n0d = n0s;
    }
#pragma unroll
    for (int p = 0; p < 4; ++p) {
        const int rr = r0 + p * 8;
        Ts[rr][cc] = W[(size_t)(k0 + rr) * ldw + n0s + cc];
    }
    __syncthreads();
#pragma unroll
    for (int p = 0; p < 4; ++p) {
        const int rr = r0 + p * 8;
        WT[(size_t)(n0d + rr) * ldwt + k0 + cc] = f2bf(Ts[cc][rr]);
    }
}

// ================= L2: qkv GEMM + vecdot GEMM =================
// blocks [0,384): qkv (64x128 tiles, A = xs_bf)
// blocks [384,896): vecdot (16 rows x 128 ch x 2 halves, A = vec_bf)
__global__ __launch_bounds__(256) void fused_mid(
    const short* __restrict__ xs_bf, const short* __restrict__ vec_bf,
    const short* __restrict__ WqkvT, const short* __restrict__ WvecT,
    const float* __restrict__ bq, const float* __restrict__ bk, const float* __restrict__ bv,
    const float* __restrict__ alpha_dot,
    short* __restrict__ Qb, short* __restrict__ Kb, short* __restrict__ Vb,
    float* __restrict__ vec_dot, short* __restrict__ inv_bf) {
    __shared__ __align__(16) short lds[22912];  // 45.8 KB
    const int bid = blockIdx.x;
    const int t = threadIdx.x, lane = t & 63, wid = t >> 6;
    const int quad = lane >> 4, lm = lane & 15;

    if (bid < 384) {
        // ----- qkv: tile 64x128, A bf16 from xs_bf -----
        short* As = lds;           // 2560
        short* Bs = lds + 2560;    // 5120
        const int row0 = (bid & 63) * 64, col0 = (bid >> 6) * 128;
        const int wm = wid & 1, wn = wid >> 1;
        const int srow = t >> 2, scg = (t & 3) * 8;
        f32x4 acc[2][4];
#pragma unroll
        for (int mt = 0; mt < 2; ++mt)
#pragma unroll
            for (int nt = 0; nt < 4; ++nt) {
                f32x4 z = {0.f, 0.f, 0.f, 0.f};
                acc[mt][nt] = z;
            }
        bf16x8 pa = *(const bf16x8*)&xs_bf[(size_t)(row0 + srow) * 256 + scg];
        bf16x8 pb[2];
#pragma unroll
        for (int p = 0; p < 2; ++p) {
            const int idx = t + p * 256;
            pb[p] = *(const bf16x8*)&WqkvT[(size_t)(col0 + (idx >> 2)) * 256 + (idx & 3) * 8];
        }
        for (int k0 = 0; k0 < 256; k0 += 32) {
            *(bf16x8*)&As[srow * 40 + scg] = pa;
#pragma unroll
            for (int p = 0; p < 2; ++p) {
                const int idx = t + p * 256;
                *(bf16x8*)&Bs[(idx >> 2) * 40 + (idx & 3) * 8] = pb[p];
            }
            __syncthreads();
            if (k0 + 32 < 256) {
                pa = *(const bf16x8*)&xs_bf[(size_t)(row0 + srow) * 256 + k0 + 32 + scg];
#pragma unroll
                for (int p = 0; p < 2; ++p) {
                    const int idx = t + p * 256;
                    pb[p] = *(const bf16x8*)&WqkvT[(size_t)(col0 + (idx >> 2)) * 256 + k0 + 32 + (idx & 3) * 8];
                }
            }
            bf16x8 af[2], bfr[4];
#pragma unroll
            for (int mt = 0; mt < 2; ++mt)
                af[mt] = *(bf16x8*)&As[(wm * 32 + mt * 16 + lm) * 40 + quad * 8];
#pragma unroll
            for (int nt = 0; nt < 4; ++nt)
                bfr[nt] = *(bf16x8*)&Bs[(wn * 64 + nt * 16 + lm) * 40 + quad * 8];
#pragma unroll
            for (int mt = 0; mt < 2; ++mt)
#pragma unroll
                for (int nt = 0; nt < 4; ++nt)
                    acc[mt][nt] = __builtin_amdgcn_mfma_f32_16x16x32_bf16(
                        af[mt], bfr[nt], acc[mt][nt], 0, 0, 0);
            __syncthreads();
        }
        const int chunk = col0 >> 8;
        short* dst = chunk == 0 ? Qb : (chunk == 1 ? Kb : Vb);
        const float* bias = chunk == 0 ? bq : (chunk == 1 ? bk : bv);
#pragma unroll
        for (int mt = 0; mt < 2; ++mt)
#pragma unroll
            for (int nt = 0; nt < 4; ++nt) {
                const int cm = (col0 + wn * 64 + nt * 16 + lm) & 255;
                const float bb = bias[cm];
#pragma unroll
                for (int r = 0; r < 4; ++r) {
                    const int row = row0 + wm * 32 + mt * 16 + quad * 4 + r;
                    dst[(size_t)row * 256 + cm] = f2bf(acc[mt][nt][r] + bb);
                }
            }
        return;
    }

    // ----- vecdot: 16 rows x (128 ch x 2 halves); A staged once -----
    short* As = lds;            // 3 x 16 x 264 = 12672
    short* Bs = lds + 12672;    // 2 x 128 x 40 = 10240
    const int vb = bid - 384;
    const int row0 = (vb >> 1) * 16, ch0 = (vb & 1) * 128;

#pragma unroll
    for (int q = 0; q < 6; ++q) {
        const int idx = t + q * 256;          // [0,1536)
        const int p = idx >> 9, rem = idx & 511, row = rem >> 5, kg = rem & 31;
        *(bf16x8*)&As[(p * 16 + row) * 264 + kg * 8] =
            *(const bf16x8*)&vec_bf[((size_t)p * BN + row0 + row) * 256 + kg * 8];
    }
    f32x4 acc[3][2][2];  // [plane][half][nt]
#pragma unroll
    for (int p = 0; p < 3; ++p)
#pragma unroll
        for (int h = 0; h < 2; ++h)
#pragma unroll
            for (int nt = 0; nt < 2; ++nt) {
                f32x4 z = {0.f, 0.f, 0.f, 0.f};
                acc[p][h][nt] = z;
            }
    bf16x8 pb[4];
#pragma unroll
    for (int q = 0; q < 4; ++q) {
        const int idx = t + q * 256;          // [0,1024)
        const int h = idx >> 9, rem = idx & 511, c = rem >> 2, kg = rem & 3;
        pb[q] = *(const bf16x8*)&WvecT[(size_t)(h * 256 + ch0 + c) * 256 + kg * 8];
    }
    __syncthreads();
    for (int k0 = 0; k0 < 256; k0 += 32) {
#pragma unroll
        for (int q = 0; q < 4; ++q) {
            const int idx = t + q * 256;
            const int h = idx >> 9, rem = idx & 511, c = rem >> 2, kg = rem & 3;
            *(bf16x8*)&Bs[(h * 128 + c) * 40 + kg * 8] = pb[q];
        }
        __syncthreads();
        if (k0 + 32 < 256) {
#pragma unroll
            for (int q = 0; q < 4; ++q) {
                const int idx = t + q * 256;
                const int h = idx >> 9, rem = idx & 511, c = rem >> 2, kg = rem & 3;
                pb[q] = *(const bf16x8*)&WvecT[(size_t)(h * 256 + ch0 + c) * 256 + k0 + 32 + kg * 8];
            }
        }
        bf16x8 af[3], bfr[2][2];
#pragma unroll
        for (int p = 0; p < 3; ++p)
            af[p] = *(bf16x8*)&As[(p * 16 + lm) * 264 + k0 + quad * 8];
#pragma unroll
        for (int h = 0; h < 2; ++h)
#pragma unroll
            for (int nt = 0; nt < 2; ++nt)
                bfr[h][nt] = *(bf16x8*)&Bs[(h * 128 + wid * 32 + nt * 16 + lm) * 40 + quad * 8];
#pragma unroll
        for (int p = 0; p < 3; ++p)
#pragma unroll
            for (int h = 0; h < 2; ++h)
#pragma unroll
                for (int nt = 0; nt < 2; ++nt)
                    acc[p][h][nt] = __builtin_amdgcn_mfma_f32_16x16x32_bf16(
                        af[p], bfr[h][nt], acc[p][h][nt], 0, 0, 0);
        __syncthreads();
    }
    const float ad = alpha_dot[0];
#pragma unroll
    for (int nt = 0; nt < 2; ++nt) {
        const int col = ch0 + wid * 32 + nt * 16 + lm;
#pragma unroll
        for (int r = 0; r < 4; ++r) {
            const int row = row0 + quad * 4 + r;
            float dot = 0.f;
#pragma unroll
            for (int p = 0; p < 3; ++p)
                dot = fmaf(acc[p][0][nt][r], acc[p][1][nt][r], dot);
            vec_dot[(size_t)row * 256 + col] = dot;
            inv_bf[(size_t)row * 512 + col] = f2bf(ad * dot);
        }
    }
}

// ================= L3: gate GEMM + attention (parallel ranges) =================
// blocks [0,256): gate; [256,1280): attn
__global__ __launch_bounds__(256) void gate_attn_kernel(
    const short* __restrict__ inv_bf, const short* __restrict__ WgT,
    const float* __restrict__ bg,
    const short* __restrict__ Qb, const short* __restrict__ Kb,
    const short* __restrict__ Vb, const short* __restrict__ vec_bf,
    float* __restrict__ gate, float* __restrict__ attnw,
    short* __restrict__ vec_aggr_bf, short* __restrict__ xout_bf) {
    __shared__ __align__(16) short lds[21760];  // 43.5 KB
    const int bid = blockIdx.x;
    const int t = threadIdx.x, lane = t & 63, wid = t >> 6;
    const int wm = wid & 1, wn = wid >> 1, quad = lane >> 4, lm = lane & 15;

    if (bid < 256) {
        // ----- gate = sigmoid(inv @ Wg + bg), tile 64x64, K=512 -----
        short* As = lds;
        short* Bs = lds + 2560;
        const int row0 = (bid & 63) * 64, col0 = (bid >> 6) * 64;
        const int srow = t >> 2, scg = (t & 3) * 8;
        f32x4 acc[2][2];
#pragma unroll
        for (int mt = 0; mt < 2; ++mt)
#pragma unroll
            for (int nt = 0; nt < 2; ++nt) {
                f32x4 z = {0.f, 0.f, 0.f, 0.f};
                acc[mt][nt] = z;
            }
        bf16x8 pa = *(const bf16x8*)&inv_bf[(size_t)(row0 + srow) * 512 + scg];
        bf16x8 pb = *(const bf16x8*)&WgT[(size_t)(col0 + srow) * 512 + scg];
        for (int k0 = 0; k0 < 512; k0 += 32) {
            *(bf16x8*)&As[srow * 40 + scg] = pa;
            *(bf16x8*)&Bs[srow * 40 + scg] = pb;
            __syncthreads();
            if (k0 + 32 < 512) {
                pa = *(const bf16x8*)&inv_bf[(size_t)(row0 + srow) * 512 + k0 + 32 + scg];
                pb = *(const bf16x8*)&WgT[(size_t)(col0 + srow) * 512 + k0 + 32 + scg];
            }
            bf16x8 af[2], bfr[2];
#pragma unroll
            for (int mt = 0; mt < 2; ++mt)
                af[mt] = *(bf16x8*)&As[(wm * 32 + mt * 16 + lm) * 40 + quad * 8];
#pragma unroll
            for (int nt = 0; nt < 2; ++nt)
                bfr[nt] = *(bf16x8*)&Bs[(wn * 32 + nt * 16 + lm) * 40 + quad * 8];
#pragma unroll
            for (int mt = 0; mt < 2; ++mt)
#pragma unroll
                for (int nt = 0; nt < 2; ++nt)
                    acc[mt][nt] = __builtin_amdgcn_mfma_f32_16x16x32_bf16(
                        af[mt], bfr[nt], acc[mt][nt], 0, 0, 0);
            __syncthreads();
        }
#pragma unroll
        for (int mt = 0; mt < 2; ++mt)
#pragma unroll
            for (int nt = 0; nt < 2; ++nt) {
                const int col = col0 + wn * 32 + nt * 16 + lm;
                const float bb = bg[col];
#pragma unroll
                for (int r = 0; r < 4; ++r) {
                    const int row = row0 + wm * 32 + mt * 16 + quad * 4 + r;
                    const float z = acc[mt][nt][r] + bb;
                    gate[(size_t)row * 256 + col] = 1.f / (1.f + __expf(-z));
                }
            }
        return;
    }

    // ----- attention -----
    short* Qs = lds;            // 32*40
    short* Ks = lds + 1280;     // 96*40
    short* Pb = lds + 5120;     // 32*104
    short* St = lds + 8448;     // 128*104
    const int ab = bid - 256;
    const int bh = ab >> 6, tile = ab & 63;
    const int b = bh >> 3, hd = bh & 7;
    const int i0 = tile * 32;

    for (int idx = t; idx < 32 * 104 / 2; idx += 256) ((int*)Pb)[idx] = 0;
    if (t < 128) {
        const int row = t >> 2, cg = t & 3;
        *(bf16x8*)&Qs[row * 40 + cg * 8] =
            *(const bf16x8*)&Qb[((size_t)(b * Nn + i0 + row)) * 256 + hd * 32 + cg * 8];
    }
#pragma unroll
    for (int kk = 0; kk < 2; ++kk) {
        const int idx = t + kk * 256;
        if (idx < 384) {
            const int row = idx >> 2, cg = idx & 3;
            const int j = i0 - WIN + row;
            bf16x8 kv = {0, 0, 0, 0, 0, 0, 0, 0};
            if (j >= 0 && j < Nn)
                kv = *(const bf16x8*)&Kb[((size_t)(b * Nn + j)) * 256 + hd * 32 + cg * 8];
            *(bf16x8*)&Ks[row * 40 + cg * 8] = kv;
        }
    }
    __syncthreads();

    if (wid < 2) {
        const int il0 = wid * 16;
        const bf16x8 aq = *(bf16x8*)&Qs[(il0 + lm) * 40 + quad * 8];
        f32x4 c[6];
#pragma unroll
        for (int nt = 0; nt < 6; ++nt) {
            const bf16x8 bk = *(bf16x8*)&Ks[(nt * 16 + lm) * 40 + quad * 8];
            f32x4 z = {0.f, 0.f, 0.f, 0.f};
            c[nt] = __builtin_amdgcn_mfma_f32_16x16x32_bf16(aq, bk, z, 0, 0, 0);
        }
        float mx[4] = {-1e30f, -1e30f, -1e30f, -1e30f};
#pragma unroll
        for (int nt = 0; nt < 6; ++nt)
#pragma unroll
            for (int r = 0; r < 4; ++r) {
                const int il = il0 + quad * 4 + r;
                const int w = nt * 16 + lm - il;
                const float v = (w >= 0 && w <= 64)
                    ? c[nt][r] * 0.17677669529663687f : -1e30f;
                c[nt][r] = v;
                mx[r] = fmaxf(mx[r], v);
            }
#pragma unroll
        for (int off = 1; off < 16; off <<= 1)
#pragma unroll
            for (int r = 0; r < 4; ++r) mx[r] = fmaxf(mx[r], __shfl_xor(mx[r], off, 64));
        float sm[4] = {0.f, 0.f, 0.f, 0.f};
#pragma unroll
        for (int nt = 0; nt < 6; ++nt)
#pragma unroll
            for (int r = 0; r < 4; ++r) {
                const int il = il0 + quad * 4 + r;
                const int w = nt * 16 + lm - il;
                const float e = (w >= 0 && w <= 64) ? __expf(c[nt][r] - mx[r]) : 0.f;
                c[nt][r] = e;
                sm[r] += e;
            }
#pragma unroll
        for (int off = 1; off < 16; off <<= 1)
#pragma unroll
            for (int r = 0; r < 4; ++r) sm[r] += __shfl_xor(sm[r], off, 64);
        float inv[4];
#pragma unroll
        for (int r = 0; r < 4; ++r) inv[r] = 1.f / sm[r];
#pragma unroll
        for (int nt = 0; nt < 6; ++nt)
#pragma unroll
            for (int r = 0; r < 4; ++r) {
                const int il = il0 + quad * 4 + r;
                const int jr = nt * 16 + lm;
                const int w = jr - il;
                if (w >= 0 && w <= 64) {
                    const float pw = c[nt][r] * inv[r];
                    attnw[((size_t)bh * Nn + (i0 + il)) * WL + w] = pw;
                    Pb[il * 104 + jr] = f2bf(pw);
                }
            }
    } else {
        // stage S^T: V dims 0-31, vec dims 32-127; packed 4-j b64 writes
        const int tt = t - 128;
        const int chunk = tt >> 3;        // 16 chunks of 8 dims
        const int j4 = (tt & 7) * 4;      // 4 consecutive j per iter
#pragma unroll
        for (int it = 0; it < 3; ++it) {
            const int jr = j4 + it * 32;
            bf16x8 v[4];
#pragma unroll
            for (int q = 0; q < 4; ++q) {
                const int j = i0 - WIN + jr + q;
                bf16x8 val = {0, 0, 0, 0, 0, 0, 0, 0};
                if (j >= 0 && j < Nn) {
                    if (chunk < 4) {
                        val = *(const bf16x8*)&Vb[((size_t)(b * Nn + j)) * 256 + hd * 32 + chunk * 8];
                    } else {
                        const int vc = (chunk - 4) >> 2, d0 = ((chunk - 4) & 3) * 8;
                        val = *(const bf16x8*)&vec_bf[((size_t)vc * BN + b * Nn + j) * 256 + hd * 32 + d0];
                    }
                }
                v[q] = val;
            }
#pragma unroll
            for (int u = 0; u < 8; ++u) {
                s16x4 pk;
                pk[0] = v[0][u]; pk[1] = v[1][u]; pk[2] = v[2][u]; pk[3] = v[3][u];
                *(s16x4*)&St[(chunk * 8 + u) * 104 + jr] = pk;
            }
        }
    }
    __syncthreads();

    f32x4 acc[4];
#pragma unroll
    for (int nt = 0; nt < 4; ++nt) {
        f32x4 z = {0.f, 0.f, 0.f, 0.f};
        acc[nt] = z;
    }
#pragma unroll
    for (int ks = 0; ks < 3; ++ks) {
        const bf16x8 ap = *(bf16x8*)&Pb[(wm * 16 + lm) * 104 + ks * 32 + quad * 8];
#pragma unroll
        for (int nt = 0; nt < 4; ++nt) {
            const bf16x8 bs = *(bf16x8*)&St[(wn * 64 + nt * 16 + lm) * 104 + ks * 32 + quad * 8];
            acc[nt] = __builtin_amdgcn_mfma_f32_16x16x32_bf16(ap, bs, acc[nt], 0, 0, 0);
        }
    }
#pragma unroll
    for (int nt = 0; nt < 4; ++nt) {
        const int dim = wn * 64 + nt * 16 + lm;
#pragma unroll
        for (int r = 0; r < 4; ++r) {
            const int i = wm * 16 + quad * 4 + r;
            const size_t bn = (size_t)(b * Nn + i0 + i);
            if (dim < 32) {
                xout_bf[bn * 256 + hd * 32 + dim] = f2bf(acc[nt][r]);
            } else {
                const int dm = dim - 32, c = dm >> 5, dd = dm & 31;
                vec_aggr_bf[((size_t)c * BN + bn) * 256 + hd * 32 + dd] = f2bf(acc[nt][r]);
            }
        }
    }
}

// ================= L4: out projection + scalar combine + vec gating =========
// 512 blocks: 128 row-tiles (32 rows) x 4 col-tiles (64 cols)
// vec residual read from vec_bf (bf16) instead of fp32 x: -25 MB L3 traffic.
__global__ __launch_bounds__(256) void out_kernel(
    const short* __restrict__ A, const short* __restrict__ BT,
    const float* __restrict__ bo,
    const float* __restrict__ vec_dot, const float* __restrict__ vec_norm,
    const float* __restrict__ gate, const short* __restrict__ vec_aggr_bf,
    const short* __restrict__ vec_bf, float* __restrict__ out) {
    __shared__ __align__(16) short As[32 * 40];
    __shared__ __align__(16) short Bs[3][64 * 40];
    const int row0 = (blockIdx.x & 127) * 32, ch0 = (blockIdx.x >> 7) * 64;
    const int t = threadIdx.x, lane = t & 63, wid = t >> 6;
    const int wm = wid & 1, wn = wid >> 1, quad = lane >> 4, lm = lane & 15;
    f32x4 acc[3][2];
#pragma unroll
    for (int p = 0; p < 3; ++p)
#pragma unroll
        for (int nt = 0; nt < 2; ++nt) {
            f32x4 z = {0.f, 0.f, 0.f, 0.f};
            acc[p][nt] = z;
        }
    bf16x8 pa = {0, 0, 0, 0, 0, 0, 0, 0};
    const int arow = t >> 2, acg = (t & 3) * 8;
    if (t < 128) pa = *(const bf16x8*)&A[(size_t)(row0 + arow) * 256 + acg];
    bf16x8 pb[3];
#pragma unroll
    for (int q = 0; q < 3; ++q) {
        const int idx = t + q * 256;
        const int p = idx >> 8, rem = idx & 255, brow = rem >> 2, bkg = (rem & 3) * 8;
        pb[q] = *(const bf16x8*)&BT[(size_t)(p * 256 + ch0 + brow) * 256 + bkg];
    }
    for (int k0 = 0; k0 < 256; k0 += 32) {
        if (t < 128) *(bf16x8*)&As[arow * 40 + acg] = pa;
#pragma unroll
        for (int q = 0; q < 3; ++q) {
            const int idx = t + q * 256;
            const int p = idx >> 8, rem = idx & 255, brow = rem >> 2, bkg = (rem & 3) * 8;
            *(bf16x8*)&Bs[p][brow * 40 + bkg] = pb[q];
        }
        __syncthreads();
        if (k0 + 32 < 256) {
            if (t < 128) pa = *(const bf16x8*)&A[(size_t)(row0 + arow) * 256 + k0 + 32 + acg];
#pragma unroll
            for (int q = 0; q < 3; ++q) {
                const int idx = t + q * 256;
                const int p = idx >> 8, rem = idx & 255, brow = rem >> 2, bkg = (rem & 3) * 8;
                pb[q] = *(const bf16x8*)&BT[(size_t)(p * 256 + ch0 + brow) * 256 + k0 + 32 + bkg];
            }
        }
        const bf16x8 af = *(bf16x8*)&As[(wm * 16 + lm) * 40 + quad * 8];
        bf16x8 bfr[3][2];
#pragma unroll
        for (int p = 0; p < 3; ++p)
#pragma unroll
            for (int nt = 0; nt < 2; ++nt)
                bfr[p][nt] = *(bf16x8*)&Bs[p][(wn * 32 + nt * 16 + lm) * 40 + quad * 8];
#pragma unroll
        for (int p = 0; p < 3; ++p)
#pragma unroll
            for (int nt = 0; nt < 2; ++nt)
                acc[p][nt] = __builtin_amdgcn_mfma_f32_16x16x32_bf16(
                    af, bfr[p][nt], acc[p][nt], 0, 0, 0);
        __syncthreads();
    }
#pragma unroll
    for (int nt = 0; nt < 2; ++nt) {
        const int col = ch0 + wn * 32 + nt * 16 + lm;
        const float b1 = bo[col], b2 = bo[256 + col], b3 = bo[512 + col];
#pragma unroll
        for (int r = 0; r < 4; ++r) {
            const int row = row0 + wm * 16 + quad * 4 + r;
            const float o1 = acc[0][nt][r] + b1;
            const float o2 = acc[1][nt][r] + b2;
            const float o3 = acc[2][nt][r] + b3;
            const float vd = vec_dot[(size_t)row * 256 + col];
            const float vn = vec_norm[(size_t)row * 256 + col];
            out[(size_t)row * 1024 + col] = vd * o1 + vn * o2 + o3;
        }
    }
    // vec channels: out = gate * vec_aggr + vec  (vec from bf16 copy)
#pragma unroll
    for (int c = 0; c < 3; ++c) {
#pragma unroll
        for (int it = 0; it < 2; ++it) {
            const int idx = t + it * 256;
            const int row = row0 + (idx >> 4), col = ch0 + (idx & 15) * 4;
            const float4 g4 = *(const float4*)&gate[(size_t)row * 256 + col];
            const s16x4 va = *(const s16x4*)&vec_aggr_bf[((size_t)c * BN + row) * 256 + col];
            const s16x4 xv = *(const s16x4*)&vec_bf[((size_t)c * BN + row) * 256 + col];
            float4 o;
            o.x = fmaf(g4.x, bf2f(va[0]), bf2f(xv[0]));
            o.y = fmaf(g4.y, bf2f(va[1]), bf2f(xv[1]));
            o.z = fmaf(g4.z, bf2f(va[2]), bf2f(xv[2]));
            o.w = fmaf(g4.w, bf2f(va[3]), bf2f(xv[3]));
            *(float4*)&out[(size_t)row * 1024 + (1 + c) * 256 + col] = o;
        }
    }
}

extern "C" void kernel_launch(void* const* d_in, const int* in_sizes, int n_in,
                              void* d_out, int out_size, void* d_ws, size_t ws_size,
                              hipStream_t stream) {
    const float* x  = (const float*)d_in[0];
    const float* Wq = (const float*)d_in[1];
    const float* bq = (const float*)d_in[2];
    const float* Wk = (const float*)d_in[3];
    const float* bk = (const float*)d_in[4];
    const float* Wv = (const float*)d_in[5];
    const float* bv = (const float*)d_in[6];
    const float* Wo = (const float*)d_in[7];
    const float* bo = (const float*)d_in[8];
    const float* Wvec = (const float*)d_in[9];
    const float* alpha_dot  = (const float*)d_in[10];
    const float* alpha_norm = (const float*)d_in[11];
    const float* Wg = (const float*)d_in[12];
    const float* bg = (const float*)d_in[13];

    float* ws = (float*)d_ws;
    float* vec_dot  = ws;              // 1048576
    float* vec_norm = ws + 1048576;    // 1048576
    float* gate     = ws + 2097152;    // 1048576
    short* sb = (short*)(ws + 3145728);
    short* xs_bf       = sb;               // 1048576
    short* vec_bf      = sb + 1048576;     // 3145728
    short* inv_bf      = sb + 4194304;     // 2097152
    short* xout_bf     = sb + 6291456;     // 1048576
    short* Q_bf        = sb + 7340032;     // 1048576
    short* K_bf        = sb + 8388608;     // 1048576
    short* V_bf        = sb + 9437184;     // 1048576
    short* vec_aggr_bf = sb + 10485760;    // 3145728
    short* WqkvT       = sb + 13631488;    // 196608
    short* WvecT       = sb + 13828096;    // 131072
    short* WgT         = sb + 13959168;    // 131072
    short* WoT         = sb + 14090240;    // 196608

    float* out = (float*)d_out;
    float* attnw = out + (size_t)Bc * Nn * 4 * Hh;  // offset 4,194,304

    castxw_kernel<<<1152, 256, 0, stream>>>(x, alpha_norm, Wq, Wk, Wv, Wvec, Wg, Wo,
                                            xs_bf, vec_bf, vec_norm, inv_bf,
                                            WqkvT, WvecT, WgT, WoT);
    fused_mid<<<896, 256, 0, stream>>>(xs_bf, vec_bf, WqkvT, WvecT, bq, bk, bv,
                                       alpha_dot, Q_bf, K_bf, V_bf, vec_dot, inv_bf);
    gate_attn_kernel<<<1280, 256, 0, stream>>>(inv_bf, WgT, bg, Q_bf, K_bf, V_bf,
                                               vec_bf, gate, attnw, vec_aggr_bf, xout_bf);
    out_kernel<<<512, 256, 0, stream>>>(xout_bf, WoT, bo, vec_dot, vec_norm,
                                        gate, vec_aggr_bf, vec_bf, out);
}